// Round 11
// baseline (85.123 us; speedup 1.0000x reference)
//
#include <hip/hip_runtime.h>

#define HID 64
#define NTOK 66          // VOCAB_SIZE + 2
#define SEQ 64
#define WIN0 55          // SEQ_LEN - 1 - MEMORY_SLOTS
#define NW 8
#define LDS_STRIDE 72    // ushorts per table row (144B; token -> bank-quad uniform)
#define ITERS 8          // iterations per block (rows/block = 512, grid = 1024)
#define ROWS_PER_ITER 64 // 4 waves x 16 rows

typedef _Float16 half8 __attribute__((ext_vector_type(8)));
typedef unsigned short ushort8v __attribute__((ext_vector_type(8)));
typedef float float4v __attribute__((ext_vector_type(4)));

static __device__ __forceinline__ unsigned short f2h(float f) {
    _Float16 h = (_Float16)f;
    union { _Float16 h; unsigned short u; } v; v.h = h;
    return v.u;
}

// Kernel 1: tables T1[t][n] = b1[n] + sum_k emb[t][k]*W1[n][k]
//           T2[t][n] = 0.125 * sum_k emb[t][k]*W1[n][64+k]
// stored F16 in ws: [2][66][64]
__global__ void build_tables(const float* __restrict__ embed,
                             const float* __restrict__ W1,
                             const float* __restrict__ b1,
                             unsigned short* __restrict__ tbl) {
    int b = blockIdx.x;      // 0..131
    int tb = b & 1;
    int t  = b >> 1;
    int n  = threadIdx.x;    // 0..63
    float acc = tb ? 0.0f : b1[n];
    const float* er = embed + t * HID;
    const float* wr = W1 + n * (2 * HID) + tb * HID;
#pragma unroll 8
    for (int k = 0; k < HID; ++k) acc += er[k] * wr[k];
    if (tb) acc *= 0.125f;
    tbl[tb * (NTOK * HID) + t * HID + n] = f2h(acc);
}

// Kernel 2: logits^T = W2 (A-op) x h^T (B-op) via mfma_f32_16x16x32_f16.
// ROTATING SINGLE-BUFFER gather pipeline: g[9] holds one chunk's 9 LDS rows
// (T1[q] + 8x T2[w]). Each consume (s += g[j]) immediately reissues g[j]
// as the NEXT chunk's read -> LDS latency hides under the f16 add tree and
// the split MFMA (kc0 after a0, kc1+stores after a1). Zero extra stage
// arrays beyond the 36 VGPRs that were already transiently live.
__global__ __launch_bounds__(256, 4) void fused_forward(
    const int* __restrict__ seqs,
    const int* __restrict__ qtok,
    const float* __restrict__ W2,
    const float* __restrict__ b2,
    const unsigned short* __restrict__ tbl,
    float* __restrict__ out)
{
    __shared__ unsigned short T_lds[2 * NTOK * LDS_STRIDE]; // 19008 B

    int tid  = threadIdx.x;
    int wv   = tid >> 6;
    int l    = tid & 63;
    int lrow = l & 15;          // W2 row within n-tile / batch row within tile
    int lg   = l >> 4;
    int lk8  = lg * 8;          // k offset within 32-wide K chunk

    int row0 = blockIdx.x * (ITERS * ROWS_PER_ITER) + wv * 16 + lrow;

    int qA, qB;
    int wA[NW], wB[NW];
    half8  g[9];                // rotating stage: [0..7]=T2 rows, [8]=T1 row
    half8  a0, a1;
    float4v acc4[4];

// scalar token loads (proven-clean HBM traffic)
#define LOADT(s, t_) { \
    int row_ = row0 + (t_) * ROWS_PER_ITER; \
    q##s = qtok[row_]; \
    const int* sp_ = seqs + row_ * SEQ + WIN0; \
    _Pragma("unroll") \
    for (int j = 0; j < NW; ++j) w##s[j] = sp_[j]; \
}

// fill the stage buffer for one chunk (prologue only)
#define GATHER_ALL(qq, ww, k0c) { \
    g[8] = *(const half8*)(T_lds + (qq) * LDS_STRIDE + (k0c)); \
    _Pragma("unroll") \
    for (int j = 0; j < NW; ++j) \
        g[j] = *(const half8*)(T_lds + NTOK * LDS_STRIDE + (ww)[j] * LDS_STRIDE + (k0c)); \
}

// consume stage (sum+relu) while REISSUING each slot for the next chunk
#define SUM_REISSUE(aout, qq, ww, k0c) { \
    half8 s_ = g[8]; \
    g[8] = *(const half8*)(T_lds + (qq) * LDS_STRIDE + (k0c)); \
    _Pragma("unroll") \
    for (int j = 0; j < NW; ++j) { \
        s_ += g[j]; \
        g[j] = *(const half8*)(T_lds + NTOK * LDS_STRIDE + (ww)[j] * LDS_STRIDE + (k0c)); \
    } \
    half8 z_ = (half8)(_Float16)0; \
    aout = __builtin_elementwise_max(s_, z_); \
}

// final consume, no reissue
#define SUM_FINAL(aout) { \
    half8 s_ = g[8]; \
    _Pragma("unroll") \
    for (int j = 0; j < NW; ++j) s_ += g[j]; \
    half8 z_ = (half8)(_Float16)0; \
    aout = __builtin_elementwise_max(s_, z_); \
}

// first K-half of the MFMAs (C init = bias); runs under chunk1 read latency
#define MFMA_K0 { \
    _Pragma("unroll") \
    for (int nt = 0; nt < 4; ++nt) \
        acc4[nt] = __builtin_amdgcn_mfma_f32_16x16x32_f16(wfrag[nt][0], a0, b2v[nt], 0, 0, 0); \
}

// second K-half + stores; runs under next-iter chunk0 read latency
#define MFMA_K1_ST(t_) { \
    float* op = out + (size_t)(row0 + (t_) * ROWS_PER_ITER) * HID; \
    _Pragma("unroll") \
    for (int nt = 0; nt < 4; ++nt) { \
        acc4[nt] = __builtin_amdgcn_mfma_f32_16x16x32_f16(wfrag[nt][1], a1, acc4[nt], 0, 0, 0); \
        *(float4v*)(op + nt * 16 + lg * 4) = acc4[nt]; \
    } \
}

// one pipelined iteration: consume C-chunk0 (reissue C-chunk1), MFMA kc0,
// consume C-chunk1 (reissue N-chunk0), MFMA kc1 + store, prefetch tokens t+2
#define ITER_MID(C, N, t_) { \
    SUM_REISSUE(a0, q##C, w##C, 32 + lk8); \
    MFMA_K0; \
    SUM_REISSUE(a1, q##N, w##N, lk8); \
    MFMA_K1_ST(t_); \
    LOADT(C, (t_) + 2); \
}
#define ITER_NOLOAD(C, N, t_) { \
    SUM_REISSUE(a0, q##C, w##C, 32 + lk8); \
    MFMA_K0; \
    SUM_REISSUE(a1, q##N, w##N, lk8); \
    MFMA_K1_ST(t_); \
}
#define ITER_LAST(C, t_) { \
    SUM_REISSUE(a0, q##C, w##C, 32 + lk8); \
    MFMA_K0; \
    SUM_FINAL(a1); \
    MFMA_K1_ST(t_); \
}

    // ---- (1) iter 0/1 token loads: HBM latency hides under W2+fill+barrier ----
    LOADT(A, 0);
    LOADT(B, 1);

    // ---- (2) W2 A-fragments in registers (whole 64x64, f16) + b2 float4 ----
    half8   wfrag[4][2];
    float4v b2v[4];
#pragma unroll
    for (int nt = 0; nt < 4; ++nt) {
        b2v[nt] = *(const float4v*)(b2 + nt * 16 + lg * 4);
#pragma unroll
        for (int kc = 0; kc < 2; ++kc) {
            const float* wp = W2 + (nt * 16 + lrow) * HID + kc * 32 + lk8;
            half8 f;
#pragma unroll
            for (int j = 0; j < 8; ++j) f[j] = (_Float16)wp[j];
            wfrag[nt][kc] = f;
        }
    }

    // ---- (3) fill LDS tables (16B chunks; row stride 144B) ----
    for (int i = tid; i < 2 * NTOK * (HID / 8); i += 256) {
        int tbi = i / (NTOK * 8);
        int rem = i - tbi * (NTOK * 8);
        int t   = rem >> 3;
        int kq  = (rem & 7) << 3;
        *(ushort8v*)(T_lds + tbi * (NTOK * LDS_STRIDE) + t * LDS_STRIDE + kq) =
            *(const ushort8v*)(tbl + tbi * (NTOK * HID) + t * HID + kq);
    }
    __syncthreads();

    // ---- (4) rotating-buffer pipeline over 8 iterations (all static) ----
    GATHER_ALL(qA, wA, lk8);    // prologue: iter0 chunk0

    ITER_MID(A, B, 0);
    ITER_MID(B, A, 1);
    ITER_MID(A, B, 2);
    ITER_MID(B, A, 3);
    ITER_MID(A, B, 4);
    ITER_MID(B, A, 5);
    ITER_NOLOAD(A, B, 6);
    ITER_LAST(B, 7);

#undef LOADT
#undef GATHER_ALL
#undef SUM_REISSUE
#undef SUM_FINAL
#undef MFMA_K0
#undef MFMA_K1_ST
#undef ITER_MID
#undef ITER_NOLOAD
#undef ITER_LAST
}

extern "C" void kernel_launch(void* const* d_in, const int* in_sizes, int n_in,
                              void* d_out, int out_size, void* d_ws, size_t ws_size,
                              hipStream_t stream) {
    const int*   seqs  = (const int*)d_in[0];
    const int*   qtok  = (const int*)d_in[1];
    const float* embed = (const float*)d_in[2];
    const float* W1    = (const float*)d_in[3];
    const float* b1    = (const float*)d_in[4];
    const float* W2    = (const float*)d_in[5];
    const float* b2    = (const float*)d_in[6];
    float* out = (float*)d_out;
    unsigned short* tbl = (unsigned short*)d_ws;

    int B = in_sizes[0] / SEQ;

    build_tables<<<NTOK * 2, HID, 0, stream>>>(embed, W1, b1, tbl);

    int grid = B / (ITERS * ROWS_PER_ITER);
    fused_forward<<<grid, 256, 0, stream>>>(seqs, qtok, W2, b2, tbl, out);
}

// Round 12
// 48.816 us; speedup vs baseline: 1.7437x; 1.7437x over previous
//
#include <hip/hip_runtime.h>

#define HID 64
#define NTOK 66          // VOCAB_SIZE + 2
#define SEQ 64
#define WIN0 55          // SEQ_LEN - 1 - MEMORY_SLOTS
#define NW 8
#define LDS_STRIDE 72    // ushorts per table row (144B; token -> bank-quad uniform)
#define ITERS 8          // iterations per block (rows/block = 512, grid = 1024)
#define ROWS_PER_ITER 64 // 4 waves x 16 rows

typedef _Float16 half8 __attribute__((ext_vector_type(8)));
typedef unsigned short ushort8v __attribute__((ext_vector_type(8)));
typedef float float4v __attribute__((ext_vector_type(4)));

static __device__ __forceinline__ unsigned short f2h(float f) {
    _Float16 h = (_Float16)f;
    union { _Float16 h; unsigned short u; } v; v.h = h;
    return v.u;
}

// Kernel 1: tables T1[t][n] = b1[n] + sum_k emb[t][k]*W1[n][k]
//           T2[t][n] = 0.125 * sum_k emb[t][k]*W1[n][64+k]
// stored F16 in ws: [2][66][64]
__global__ void build_tables(const float* __restrict__ embed,
                             const float* __restrict__ W1,
                             const float* __restrict__ b1,
                             unsigned short* __restrict__ tbl) {
    int b = blockIdx.x;      // 0..131
    int tb = b & 1;
    int t  = b >> 1;
    int n  = threadIdx.x;    // 0..63
    float acc = tb ? 0.0f : b1[n];
    const float* er = embed + t * HID;
    const float* wr = W1 + n * (2 * HID) + tb * HID;
#pragma unroll 8
    for (int k = 0; k < HID; ++k) acc += er[k] * wr[k];
    if (tb) acc *= 0.125f;
    tbl[tb * (NTOK * HID) + t * HID + n] = f2h(acc);
}

// Kernel 2: logits^T = W2 (A-op) x h^T (B-op) via mfma_f32_16x16x32_f16.
// Rotating single-buffer gather pipeline (round 11) + feasible register
// budget: persistent footprint ~136 VGPR (wfrag 32, b2v 16, g 36, tokens
// 18, a0/a1 8, acc4 16, addr ~10). launch_bounds(256,4) made that budget
// 128 -> allocator collapsed to 64 + scratch spill (rounds 6/11 FETCH
// explosion). (256,3) -> budget 170, fits with slack; measured occupancy
// at 64 VGPR was only ~3 blocks/CU anyway, so no occupancy loss.
__global__ __launch_bounds__(256, 3) void fused_forward(
    const int* __restrict__ seqs,
    const int* __restrict__ qtok,
    const float* __restrict__ W2,
    const float* __restrict__ b2,
    const unsigned short* __restrict__ tbl,
    float* __restrict__ out)
{
    __shared__ unsigned short T_lds[2 * NTOK * LDS_STRIDE]; // 19008 B

    int tid  = threadIdx.x;
    int wv   = tid >> 6;
    int l    = tid & 63;
    int lrow = l & 15;          // W2 row within n-tile / batch row within tile
    int lg   = l >> 4;
    int lk8  = lg * 8;          // k offset within 32-wide K chunk

    int row0 = blockIdx.x * (ITERS * ROWS_PER_ITER) + wv * 16 + lrow;

    int qA, qB;
    int wA[NW], wB[NW];
    half8  g[9];                // rotating stage: [0..7]=T2 rows, [8]=T1 row
    half8  a0, a1;
    float4v acc4[4];

// scalar token loads (proven-clean HBM traffic)
#define LOADT(s, t_) { \
    int row_ = row0 + (t_) * ROWS_PER_ITER; \
    q##s = qtok[row_]; \
    const int* sp_ = seqs + row_ * SEQ + WIN0; \
    _Pragma("unroll") \
    for (int j = 0; j < NW; ++j) w##s[j] = sp_[j]; \
}

// fill the stage buffer for one chunk (prologue only)
#define GATHER_ALL(qq, ww, k0c) { \
    g[8] = *(const half8*)(T_lds + (qq) * LDS_STRIDE + (k0c)); \
    _Pragma("unroll") \
    for (int j = 0; j < NW; ++j) \
        g[j] = *(const half8*)(T_lds + NTOK * LDS_STRIDE + (ww)[j] * LDS_STRIDE + (k0c)); \
}

// consume stage (sum+relu) while REISSUING each slot for the next chunk
#define SUM_REISSUE(aout, qq, ww, k0c) { \
    half8 s_ = g[8]; \
    g[8] = *(const half8*)(T_lds + (qq) * LDS_STRIDE + (k0c)); \
    _Pragma("unroll") \
    for (int j = 0; j < NW; ++j) { \
        s_ += g[j]; \
        g[j] = *(const half8*)(T_lds + NTOK * LDS_STRIDE + (ww)[j] * LDS_STRIDE + (k0c)); \
    } \
    half8 z_ = (half8)(_Float16)0; \
    aout = __builtin_elementwise_max(s_, z_); \
}

// final consume, no reissue
#define SUM_FINAL(aout) { \
    half8 s_ = g[8]; \
    _Pragma("unroll") \
    for (int j = 0; j < NW; ++j) s_ += g[j]; \
    half8 z_ = (half8)(_Float16)0; \
    aout = __builtin_elementwise_max(s_, z_); \
}

// first K-half of the MFMAs (C init = bias); runs under chunk1 read latency
#define MFMA_K0 { \
    _Pragma("unroll") \
    for (int nt = 0; nt < 4; ++nt) \
        acc4[nt] = __builtin_amdgcn_mfma_f32_16x16x32_f16(wfrag[nt][0], a0, b2v[nt], 0, 0, 0); \
}

// second K-half + stores; runs under next-iter chunk0 read latency
#define MFMA_K1_ST(t_) { \
    float* op = out + (size_t)(row0 + (t_) * ROWS_PER_ITER) * HID; \
    _Pragma("unroll") \
    for (int nt = 0; nt < 4; ++nt) { \
        acc4[nt] = __builtin_amdgcn_mfma_f32_16x16x32_f16(wfrag[nt][1], a1, acc4[nt], 0, 0, 0); \
        *(float4v*)(op + nt * 16 + lg * 4) = acc4[nt]; \
    } \
}

// one pipelined iteration: consume C-chunk0 (reissue C-chunk1), MFMA kc0,
// consume C-chunk1 (reissue N-chunk0), MFMA kc1 + store, prefetch tokens t+2
#define ITER_MID(C, N, t_) { \
    SUM_REISSUE(a0, q##C, w##C, 32 + lk8); \
    MFMA_K0; \
    SUM_REISSUE(a1, q##N, w##N, lk8); \
    MFMA_K1_ST(t_); \
    LOADT(C, (t_) + 2); \
}
#define ITER_NOLOAD(C, N, t_) { \
    SUM_REISSUE(a0, q##C, w##C, 32 + lk8); \
    MFMA_K0; \
    SUM_REISSUE(a1, q##N, w##N, lk8); \
    MFMA_K1_ST(t_); \
}
#define ITER_LAST(C, t_) { \
    SUM_REISSUE(a0, q##C, w##C, 32 + lk8); \
    MFMA_K0; \
    SUM_FINAL(a1); \
    MFMA_K1_ST(t_); \
}

    // ---- (1) iter 0/1 token loads: HBM latency hides under W2+fill+barrier ----
    LOADT(A, 0);
    LOADT(B, 1);

    // ---- (2) W2 A-fragments in registers (whole 64x64, f16) + b2 float4 ----
    half8   wfrag[4][2];
    float4v b2v[4];
#pragma unroll
    for (int nt = 0; nt < 4; ++nt) {
        b2v[nt] = *(const float4v*)(b2 + nt * 16 + lg * 4);
#pragma unroll
        for (int kc = 0; kc < 2; ++kc) {
            const float* wp = W2 + (nt * 16 + lrow) * HID + kc * 32 + lk8;
            half8 f;
#pragma unroll
            for (int j = 0; j < 8; ++j) f[j] = (_Float16)wp[j];
            wfrag[nt][kc] = f;
        }
    }

    // ---- (3) fill LDS tables (16B chunks; row stride 144B) ----
    for (int i = tid; i < 2 * NTOK * (HID / 8); i += 256) {
        int tbi = i / (NTOK * 8);
        int rem = i - tbi * (NTOK * 8);
        int t   = rem >> 3;
        int kq  = (rem & 7) << 3;
        *(ushort8v*)(T_lds + tbi * (NTOK * LDS_STRIDE) + t * LDS_STRIDE + kq) =
            *(const ushort8v*)(tbl + tbi * (NTOK * HID) + t * HID + kq);
    }
    __syncthreads();

    // ---- (4) rotating-buffer pipeline over 8 iterations (all static) ----
    GATHER_ALL(qA, wA, lk8);    // prologue: iter0 chunk0

    ITER_MID(A, B, 0);
    ITER_MID(B, A, 1);
    ITER_MID(A, B, 2);
    ITER_MID(B, A, 3);
    ITER_MID(A, B, 4);
    ITER_MID(B, A, 5);
    ITER_NOLOAD(A, B, 6);
    ITER_LAST(B, 7);

#undef LOADT
#undef GATHER_ALL
#undef SUM_REISSUE
#undef SUM_FINAL
#undef MFMA_K0
#undef MFMA_K1_ST
#undef ITER_MID
#undef ITER_NOLOAD
#undef ITER_LAST
}

extern "C" void kernel_launch(void* const* d_in, const int* in_sizes, int n_in,
                              void* d_out, int out_size, void* d_ws, size_t ws_size,
                              hipStream_t stream) {
    const int*   seqs  = (const int*)d_in[0];
    const int*   qtok  = (const int*)d_in[1];
    const float* embed = (const float*)d_in[2];
    const float* W1    = (const float*)d_in[3];
    const float* b1    = (const float*)d_in[4];
    const float* W2    = (const float*)d_in[5];
    const float* b2    = (const float*)d_in[6];
    float* out = (float*)d_out;
    unsigned short* tbl = (unsigned short*)d_ws;

    int B = in_sizes[0] / SEQ;

    build_tables<<<NTOK * 2, HID, 0, stream>>>(embed, W1, b1, tbl);

    int grid = B / (ITERS * ROWS_PER_ITER);
    fused_forward<<<grid, 256, 0, stream>>>(seqs, qtok, W2, b2, tbl, out);
}